// Round 1
// baseline (458.519 us; speedup 1.0000x reference)
//
#include <hip/hip_runtime.h>

#define NF 256        // features (K)
#define NC 256        // clusters (N)
#define NSAMP 262144  // samples (M)
#define BM 64         // samples per tile
#define TILES 8       // tiles per block
#define NBLK 512      // NSAMP / (BM * TILES)
#define NTHREADS 1024 // 16 waves; wave w owns output cols [w*16, w*16+16)
#define LDA 264       // LDS A row stride (bf16): 528 B/row, 16B-aligned, 2-way bank alias (free)

typedef __attribute__((ext_vector_type(8))) short short8;
typedef __attribute__((ext_vector_type(4))) float floatx4;

// fp32 -> bf16 round-to-nearest-even (finite inputs)
__device__ __forceinline__ unsigned short f2bf(float f) {
    unsigned int u = __builtin_bit_cast(unsigned int, f);
    return (unsigned short)((u + 0x7FFFu + ((u >> 16) & 1u)) >> 16);
}

// LDS-only barrier: drain lgkm (ds writes/atomics visible), NO vmcnt(0) drain --
// global loads/stores stay in flight across this barrier.
__device__ __forceinline__ void lds_sync() {
    asm volatile("s_waitcnt lgkmcnt(0)" ::: "memory");
    __builtin_amdgcn_sched_barrier(0);
    __builtin_amdgcn_s_barrier();
}

// ---- prep: centroids fp32 -> bf16 image scaled by -2 (row-major [NC][NF]) + csq ----
// bf16(-2c) == -2*bf16(c) exactly, so the epilogue becomes a single add3.
__global__ __launch_bounds__(64)
void prep_centroids(const float* __restrict__ cent,
                    unsigned short* __restrict__ cbf,
                    float* __restrict__ csq)
{
    const int row  = blockIdx.x;    // 0..255
    const int lane = threadIdx.x;   // 0..63
    const floatx4 v = *(const floatx4*)(cent + (size_t)row * NF + lane * 4);
    ushort4 b;
    b.x = f2bf(-2.f * v.x); b.y = f2bf(-2.f * v.y);
    b.z = f2bf(-2.f * v.z); b.w = f2bf(-2.f * v.w);
    *(ushort4*)(cbf + (size_t)row * NF + lane * 4) = b;
    float s = v.x * v.x + v.y * v.y + v.z * v.z + v.w * v.w;
    s += __shfl_xor(s, 1);
    s += __shfl_xor(s, 2);
    s += __shfl_xor(s, 4);
    s += __shfl_xor(s, 8);
    s += __shfl_xor(s, 16);
    s += __shfl_xor(s, 32);
    if (lane == 0) csq[row] = s;
}

// ---- main: persistent blocks, 8 tiles of 64 samples, double-buffered pipeline ----
// Per tile t: issue loads(t+1) -> MFMA+epilogue+store(t) -> convert regs -> As[buf^1].
// Raw lgkm-only barriers keep next-tile loads and this-tile stores in flight.
__global__ __launch_bounds__(NTHREADS, 4)   // cap 128 VGPR
void cluster_soft_assign(const float* __restrict__ x,
                         const unsigned short* __restrict__ cbf,
                         const float* __restrict__ csq,
                         float* __restrict__ out)
{
    __shared__ __align__(16) unsigned short As[2][BM * LDA];  // 2 x 33792 B
    __shared__ __align__(16) float xsq[2][BM];
    __shared__ __align__(16) float rowsum[2][BM];

    const int tid  = threadIdx.x;
    const int wave = tid >> 6;      // 0..15
    const int lane = tid & 63;
    const int quad = lane >> 4;
    const int l16  = lane & 15;
    const int srow = tid >> 4;      // 0..63 : staging row
    const int sc   = tid & 15;      // 0..15 : staging chunk
    const int col0 = wave << 4;     // 16 cols per wave

    const size_t brow = (size_t)blockIdx.x * (BM * TILES);

    // persistent B fragments: wave's 16 cols x K=256 (32 VGPRs), loaded once
    // B[n][k] operand layout: n = l16, k = quad*8 + j  (16x16x32, m89-verified)
    short8 bfr[8];
    #pragma unroll
    for (int kk = 0; kk < 8; ++kk)
        bfr[kk] = *(const short8*)(cbf + ((col0 + l16) << 8) + kk * 32 + quad * 8);
    const float csv = csq[col0 + l16];

    if (tid < 2 * BM) ((float*)rowsum)[tid] = 0.f;

    // ---- prologue: load + stage tile 0 ----
    floatx4 L[4];
    {
        const float* xr = x + (brow + srow) * NF + sc * 4;
        #pragma unroll
        for (int i = 0; i < 4; ++i) L[i] = *(const floatx4*)(xr + i * 64);
        float s = 0.f;
        #pragma unroll
        for (int i = 0; i < 4; ++i) {
            const floatx4 v = L[i];
            s += v.x * v.x + v.y * v.y + v.z * v.z + v.w * v.w;
            ushort4 b;
            b.x = f2bf(v.x); b.y = f2bf(v.y); b.z = f2bf(v.z); b.w = f2bf(v.w);
            *(ushort4*)(&As[0][srow * LDA + (sc + 16 * i) * 4]) = b;
        }
        s += __shfl_xor(s, 1);
        s += __shfl_xor(s, 2);
        s += __shfl_xor(s, 4);
        s += __shfl_xor(s, 8);
        if (sc == 0) xsq[0][srow] = s;
    }
    lds_sync();

    int cur = 0;
    for (int t = 0; t < TILES; ++t) {
        // ---- issue next tile's global loads; they fly under MFMA+epilogue ----
        if (t + 1 < TILES) {
            const float* xr = x + (brow + (size_t)(t + 1) * BM + srow) * NF + sc * 4;
            #pragma unroll
            for (int i = 0; i < 4; ++i) L[i] = *(const floatx4*)(xr + i * 64);
            __builtin_amdgcn_sched_barrier(0);   // pin issue point before MFMA loop
        }
        // zero the buffer used by tile t+1's atomics (its last readers finished
        // before barrier #2 of tile t-1; visibility via this tile's barriers)
        if (tid < BM) rowsum[cur ^ 1][tid] = 0.f;

        // ---- MFMA: 4 row-tiles x 1 col-tile x 8 K-steps ----
        floatx4 acc[4];
        #pragma unroll
        for (int i = 0; i < 4; ++i) acc[i] = (floatx4){0.f, 0.f, 0.f, 0.f};
        const unsigned short* as = As[cur];
        #pragma unroll
        for (int kk = 0; kk < 8; ++kk) {
            #pragma unroll
            for (int i = 0; i < 4; ++i) {
                const short8 afr = *(const short8*)(as + (i * 16 + l16) * LDA + kk * 32 + quad * 8);
                acc[i] = __builtin_amdgcn_mfma_f32_16x16x32_bf16(afr, bfr[kk], acc[i], 0, 0, 0);
            }
        }

        // ---- epilogue: d = x^2 + (-2 x.c) + c^2; q = 1/(1+d); partial row sums ----
        // C/D layout: col = l16, row = quad*4 + reg
        #pragma unroll
        for (int i = 0; i < 4; ++i) {
            const floatx4 xv = *(const floatx4*)(&xsq[cur][i * 16 + quad * 4]);
            #pragma unroll
            for (int reg = 0; reg < 4; ++reg) {
                float d = fmaxf(xv[reg] + acc[i][reg] + csv, 0.f);
                const float q = __builtin_amdgcn_rcpf(1.f + d);
                acc[i][reg] = q;
                float v = q;
                v += __shfl_xor(v, 1);
                v += __shfl_xor(v, 2);
                v += __shfl_xor(v, 4);
                v += __shfl_xor(v, 8);
                if (l16 == 0) atomicAdd(&rowsum[cur][i * 16 + quad * 4 + reg], v);
            }
        }
        lds_sync();   // barrier #1: rowsum[cur] complete (lgkm only; loads still in flight)

        // ---- normalize + store (fire-and-forget; never drained in-loop) ----
        {
            const size_t rt = brow + (size_t)t * BM;
            #pragma unroll
            for (int i = 0; i < 4; ++i) {
                const floatx4 rv = *(const floatx4*)(&rowsum[cur][i * 16 + quad * 4]);
                float* orow = out + (rt + i * 16 + quad * 4) * NC + col0 + l16;
                #pragma unroll
                for (int reg = 0; reg < 4; ++reg)
                    orow[(size_t)reg * NC] = acc[i][reg] * __builtin_amdgcn_rcpf(rv[reg]);
            }
        }

        // ---- stage tile t+1 from the registers that landed during compute ----
        if (t + 1 < TILES) {
            float s = 0.f;
            #pragma unroll
            for (int i = 0; i < 4; ++i) {
                const floatx4 v = L[i];   // compiler inserts counted vmcnt here (stores stay in flight)
                s += v.x * v.x + v.y * v.y + v.z * v.z + v.w * v.w;
                ushort4 b;
                b.x = f2bf(v.x); b.y = f2bf(v.y); b.z = f2bf(v.z); b.w = f2bf(v.w);
                *(ushort4*)(&As[cur ^ 1][srow * LDA + (sc + 16 * i) * 4]) = b;
            }
            s += __shfl_xor(s, 1);
            s += __shfl_xor(s, 2);
            s += __shfl_xor(s, 4);
            s += __shfl_xor(s, 8);
            if (sc == 0) xsq[cur ^ 1][srow] = s;
            lds_sync();   // barrier #2: As[cur^1]/xsq[cur^1] ready
            cur ^= 1;
        }
    }
}

extern "C" void kernel_launch(void* const* d_in, const int* in_sizes, int n_in,
                              void* d_out, int out_size, void* d_ws, size_t ws_size,
                              hipStream_t stream) {
    const float* x    = (const float*)d_in[0];
    const float* cent = (const float*)d_in[1];
    float* out        = (float*)d_out;

    unsigned short* cbf = (unsigned short*)d_ws;                       // 256*256*2 = 128 KB
    float* csq          = (float*)((char*)d_ws + (size_t)NC * NF * 2); // +1 KB

    prep_centroids<<<dim3(NC), dim3(64), 0, stream>>>(cent, cbf, csq);
    cluster_soft_assign<<<dim3(NBLK), dim3(NTHREADS), 0, stream>>>(x, cbf, csq, out);
}